// Round 1
// baseline (355.805 us; speedup 1.0000x reference)
//
#include <hip/hip_runtime.h>
#include <hip/hip_bf16.h>
#include <stdint.h>

typedef __attribute__((ext_vector_type(4))) float f32x4;
typedef __attribute__((ext_vector_type(8))) short short8;

__device__ __forceinline__ ushort f2b(float f) {
    union { __hip_bfloat16 h; ushort u; } c;
    c.h = __float2bfloat16(f);
    return c.u;
}

// async global->LDS, 16B per lane. LDS dest must be wave-uniform; HW adds lane*16.
__device__ __forceinline__ void gload_lds16(const void* g, void* lds) {
    __builtin_amdgcn_global_load_lds((const __attribute__((address_space(1))) void*)g,
                                     (__attribute__((address_space(3))) void*)lds,
                                     16, 0, 0);
}

// ---- pre-pass: x fp32 -> bf16 -----------------------------------------------
__global__ void conv_x_kernel(const float* __restrict__ x, ushort* __restrict__ xb, int n4) {
    int i = blockIdx.x * blockDim.x + threadIdx.x;
    int stride = gridDim.x * blockDim.x;
    const float4* xv = (const float4*)x;
    ushort4* ov = (ushort4*)xb;
    for (; i < n4; i += stride) {
        float4 v = xv[i];
        ushort4 r;
        r.x = f2b(v.x); r.y = f2b(v.y); r.z = f2b(v.z); r.w = f2b(v.w);
        ov[i] = r;
    }
}

// ---- pre-pass: w fp32 * blockscale -> bf16 ----------------------------------
__global__ void conv_w_kernel(const float* __restrict__ w, const float* __restrict__ sinv,
                              ushort* __restrict__ wb, int K, int n4) {
    int i = blockIdx.x * blockDim.x + threadIdx.x;
    int stride = gridDim.x * blockDim.x;
    const float4* wv = (const float4*)w;
    ushort4* ov = (ushort4*)wb;
    const int nbk = K >> 7;  // K/128
    for (; i < n4; i += stride) {
        int e = i << 2;           // element index (4-aligned, so same 128-block)
        int o = e / K;
        int ic = e - o * K;
        float s = sinv[(o >> 7) * nbk + (ic >> 7)];
        float4 v = wv[i];
        ushort4 r;
        r.x = f2b(v.x * s); r.y = f2b(v.y * s); r.z = f2b(v.z * s); r.w = f2b(v.w * s);
        ov[i] = r;
    }
}

// ---- main GEMM: C[M][N] = A[M][K] * B[N][K]^T + bias, bf16 in / fp32 out ----
// m97 structure: 128x128 tile, BK=64, 4 waves (2x2), 4x4 16x16x32 frags/wave,
// global_load_lds width=16 staging, single LDS buffer, 2 barriers/K-step.
__global__ __launch_bounds__(256)
void gemm_bf16_kernel(const ushort* __restrict__ A,   // [M][K] bf16 bits
                      const ushort* __restrict__ Bm,  // [N][K] bf16 bits
                      const float* __restrict__ bias,
                      float* __restrict__ C, int M, int N, int K) {
    __shared__ alignas(16) short lsA[128 * 64];
    __shared__ alignas(16) short lsB[128 * 64];

    const int tid  = threadIdx.x;
    const int lane = tid & 63;
    const int wid  = tid >> 6;
    const int nbn  = N >> 7;
    const int bm   = blockIdx.x / nbn;
    const int bn   = blockIdx.x % nbn;
    const int wr   = wid >> 1;   // wave row (0..1), 64 rows each
    const int wc   = wid & 1;    // wave col (0..1), 64 cols each

    const short* gA = (const short*)A;
    const short* gB = (const short*)Bm;

    // staging offsets: chunk c = wid*4+j covers rows c*8..c*8+8 of the tile;
    // lane covers row c*8 + lane/8, cols (lane&7)*8 .. +8 (16B).
    size_t aOff[4], bOff[4];
#pragma unroll
    for (int j = 0; j < 4; ++j) {
        int c   = wid * 4 + j;
        int rA  = bm * 128 + c * 8 + (lane >> 3);
        int rB  = bn * 128 + c * 8 + (lane >> 3);
        int col = (lane & 7) * 8;
        aOff[j] = (size_t)rA * K + col;
        bOff[j] = (size_t)rB * K + col;
    }

    f32x4 acc[4][4] = {};

    const int nkt = K >> 6;  // K/64
    for (int kt = 0; kt < nkt; ++kt) {
        const int kbase = kt * 64;
#pragma unroll
        for (int j = 0; j < 4; ++j) {
            int c = wid * 4 + j;
            gload_lds16(gA + aOff[j] + kbase, &lsA[c * 512]);
            gload_lds16(gB + bOff[j] + kbase, &lsB[c * 512]);
        }
        __syncthreads();  // compiler drains vmcnt(0) before barrier

#pragma unroll
        for (int kk = 0; kk < 2; ++kk) {
            short8 a[4], b[4];
#pragma unroll
            for (int m = 0; m < 4; ++m)
                a[m] = *(const short8*)&lsA[(wr * 64 + m * 16 + (lane & 15)) * 64 + kk * 32 + (lane >> 4) * 8];
#pragma unroll
            for (int n = 0; n < 4; ++n)
                b[n] = *(const short8*)&lsB[(wc * 64 + n * 16 + (lane & 15)) * 64 + kk * 32 + (lane >> 4) * 8];
#pragma unroll
            for (int m = 0; m < 4; ++m)
#pragma unroll
                for (int n = 0; n < 4; ++n)
                    acc[m][n] = __builtin_amdgcn_mfma_f32_16x16x32_bf16(a[m], b[n], acc[m][n], 0, 0, 0);
        }
        __syncthreads();
    }

    // epilogue: C[row][col], row = (lane>>4)*4 + reg, col = lane&15 (m89-verified)
    const int r0 = bm * 128 + wr * 64 + (lane >> 4) * 4;
    const int c0 = bn * 128 + wc * 64 + (lane & 15);
#pragma unroll
    for (int n = 0; n < 4; ++n) {
        float bv = bias[c0 + n * 16];
#pragma unroll
        for (int m = 0; m < 4; ++m) {
#pragma unroll
            for (int r = 0; r < 4; ++r) {
                C[(size_t)(r0 + m * 16 + r) * N + (c0 + n * 16)] = acc[m][n][r] + bv;
            }
        }
    }
}

// ---- fallback (only if ws too small): slow but correct ----------------------
__global__ void fallback_gemm(const float* __restrict__ x, const float* __restrict__ w,
                              const float* __restrict__ sinv, const float* __restrict__ bias,
                              float* __restrict__ out, int M, int N, int K) {
    int n = blockIdx.x * 64 + (threadIdx.x & 63);
    int m = blockIdx.y * 4 + (threadIdx.x >> 6);
    if (m >= M || n >= N) return;
    const int nbk = K >> 7;
    float acc = 0.f;
    for (int k = 0; k < K; ++k)
        acc += x[(size_t)m * K + k] * w[(size_t)n * K + k] * sinv[(n >> 7) * nbk + (k >> 7)];
    out[(size_t)m * N + n] = acc + bias[n];
}

extern "C" void kernel_launch(void* const* d_in, const int* in_sizes, int n_in,
                              void* d_out, int out_size, void* d_ws, size_t ws_size,
                              hipStream_t stream) {
    const float* x    = (const float*)d_in[0];
    const float* w    = (const float*)d_in[1];
    const float* sinv = (const float*)d_in[2];
    const float* bias = (const float*)d_in[3];
    float* out        = (float*)d_out;

    const int O = in_sizes[3];                 // 4096
    const int K = in_sizes[1] / O;             // 4096
    const int M = (int)((long)in_sizes[0] / K);// B*S = 4096
    const int N = O;

    size_t need = ((size_t)M * K + (size_t)N * K) * sizeof(ushort);
    if (ws_size >= need && (M % 128 == 0) && (N % 128 == 0) && (K % 64 == 0)) {
        ushort* xb = (ushort*)d_ws;
        ushort* wb = xb + (size_t)M * K;
        int n4x = (int)(((long)M * K) / 4);
        int n4w = (int)(((long)N * K) / 4);
        conv_x_kernel<<<dim3(2048), 256, 0, stream>>>(x, xb, n4x);
        conv_w_kernel<<<dim3(2048), 256, 0, stream>>>(w, sinv, wb, K, n4w);
        int grid = (M / 128) * (N / 128);
        gemm_bf16_kernel<<<dim3(grid), 256, 0, stream>>>(xb, wb, bias, out, M, N, K);
    } else {
        dim3 g(N / 64, (M + 3) / 4);
        fallback_gemm<<<g, 256, 0, stream>>>(x, w, sinv, bias, out, M, N, K);
    }
}

// Round 2
// 293.002 us; speedup vs baseline: 1.2143x; 1.2143x over previous
//
#include <hip/hip_runtime.h>
#include <hip/hip_bf16.h>
#include <stdint.h>

typedef __attribute__((ext_vector_type(4))) float f32x4;
typedef __attribute__((ext_vector_type(8))) short short8;

__device__ __forceinline__ ushort f2b(float f) {
    union { __hip_bfloat16 h; ushort u; } c;
    c.h = __float2bfloat16(f);
    return c.u;
}

// async global->LDS, 16B per lane. LDS dest is wave-uniform; HW adds lane*16.
__device__ __forceinline__ void gload_lds16(const void* g, void* lds) {
    __builtin_amdgcn_global_load_lds((const __attribute__((address_space(1))) void*)g,
                                     (__attribute__((address_space(3))) void*)lds,
                                     16, 0, 0);
}

#define BARRIER()  asm volatile("s_barrier" ::: "memory")
#define LGKM0()    asm volatile("s_waitcnt lgkmcnt(0)" ::: "memory")
#define VMCNT2()   asm volatile("s_waitcnt vmcnt(2)" ::: "memory")

// ---- pre-pass: x fp32 -> bf16 (8 elems/thread, one shot) --------------------
__global__ void conv_x_kernel(const float* __restrict__ x, ushort* __restrict__ xb, long n8) {
    long i = (long)blockIdx.x * blockDim.x + threadIdx.x;
    if (i >= n8) return;
    const float4* xv = (const float4*)x;
    float4 v0 = xv[i * 2], v1 = xv[i * 2 + 1];
    short8 r;
    r[0] = (short)f2b(v0.x); r[1] = (short)f2b(v0.y); r[2] = (short)f2b(v0.z); r[3] = (short)f2b(v0.w);
    r[4] = (short)f2b(v1.x); r[5] = (short)f2b(v1.y); r[6] = (short)f2b(v1.z); r[7] = (short)f2b(v1.w);
    *(short8*)&xb[i * 8] = r;
}

// ---- pre-pass: w fp32 * blockscale -> bf16 (row-indexed, div-free) ----------
__global__ void conv_w_kernel(const float* __restrict__ w, const float* __restrict__ sinv,
                              ushort* __restrict__ wb, int K, int nbk) {
    const int o = blockIdx.y;
    const int c = (blockIdx.x * blockDim.x + threadIdx.x) * 8;
    if (c >= K) return;
    const float s = sinv[(o >> 7) * nbk + (c >> 7)];
    const float4* wv = (const float4*)(w + (size_t)o * K + c);
    float4 v0 = wv[0], v1 = wv[1];
    short8 r;
    r[0] = (short)f2b(v0.x * s); r[1] = (short)f2b(v0.y * s); r[2] = (short)f2b(v0.z * s); r[3] = (short)f2b(v0.w * s);
    r[4] = (short)f2b(v1.x * s); r[5] = (short)f2b(v1.y * s); r[6] = (short)f2b(v1.z * s); r[7] = (short)f2b(v1.w * s);
    *(short8*)&wb[(size_t)o * K + c] = r;
}

// ---- main GEMM: 256x256 tile, BK=64, 8 waves (2Mx4N), 8-phase pipeline ------
// C[M][N] = A[M][K] * B[N][K]^T + bias.  bf16 in / fp32 out.
// LDS: 2 K-tile double buffer, A+B, XOR-swizzled (pre-swizzled global source).
__global__ __launch_bounds__(512, 2)
void gemm256_kernel(const ushort* __restrict__ A, const ushort* __restrict__ Bm,
                    const float* __restrict__ bias, float* __restrict__ C,
                    int M, int N, int K) {
    __shared__ alignas(16) short sm[2][32768];   // [buf][ A:16384 shorts | B:16384 shorts ]

    const int tid  = threadIdx.x;
    const int lane = tid & 63;
    const int wid  = tid >> 6;
    const int wr   = wid >> 2;          // 0..1  -> 128-row slice
    const int wc   = wid & 3;           // 0..3  -> 64-col slice
    const int nbn  = N >> 8;

    // XCD-aware bijective swizzle (launcher guarantees gridDim.x % 8 == 0)
    const int nwg = gridDim.x;
    const int swz = (blockIdx.x & 7) * (nwg >> 3) + (blockIdx.x >> 3);
    const int bm  = swz / nbn;
    const int bn  = swz % nbn;

    const short* gA = (const short*)A + (size_t)bm * 256 * K;
    const short* gB = (const short*)Bm + (size_t)bn * 256 * K;

    // staging source: unit U = 64 rows x 64 cols; wave w covers rows U*64+w*8..+7.
    // global col pre-swizzled so linear LDS write == XOR-swizzled layout.
    const int srow = wid * 8 + (lane >> 3);                 // row within unit (0..63)
    const int scol = ((lane & 7) ^ (lane >> 3)) << 3;       // elements

    auto STAGE_A = [&](int U, int kt, int buf) {
        const short* src = gA + (size_t)(U * 64 + srow) * K + kt * 64 + scol;
        gload_lds16(src, &sm[buf][U * 4096 + wid * 512]);
    };
    auto STAGE_B = [&](int U, int kt, int buf) {
        const short* src = gB + (size_t)(U * 64 + srow) * K + kt * 64 + scol;
        gload_lds16(src, &sm[buf][16384 + U * 4096 + wid * 512]);
    };

    // fragment reads (swizzled): row*64 + ((kk*32 + (lane>>4)*8) ^ ((lane&7)<<3))
    auto LD_A = [&](const short* Ab, int mh, int kk, short8 (&a)[4]) {
#pragma unroll
        for (int m = 0; m < 4; ++m) {
            int row = wr * 128 + mh * 64 + m * 16 + (lane & 15);
            a[m] = *(const short8*)&Ab[row * 64 + ((kk * 32 + (lane >> 4) * 8) ^ ((lane & 7) << 3))];
        }
    };
    auto LD_B = [&](const short* Bb, int kk, short8 (&b)[4]) {
#pragma unroll
        for (int n = 0; n < 4; ++n) {
            int row = wc * 64 + n * 16 + (lane & 15);
            b[n] = *(const short8*)&Bb[row * 64 + ((kk * 32 + (lane >> 4) * 8) ^ ((lane & 7) << 3))];
        }
    };

    f32x4 acc[8][4] = {};

    const int nkt = K >> 6;

    // ---- prologue: tile0 (8 units) + tile1 A-U0,U2 (2 units); leave 2 in flight
    {
#pragma unroll
        for (int U = 0; U < 4; ++U) STAGE_A(U, 0, 0);
#pragma unroll
        for (int U = 0; U < 4; ++U) STAGE_B(U, 0, 0);
        const int t1 = (nkt > 1) ? 1 : 0;
        STAGE_A(0, t1, 1);
        STAGE_A(2, t1, 1);
        VMCNT2();
        BARRIER();
    }

    for (int t = 0; t < nkt; ++t) {
        const int b  = t & 1;
        const short* Ab = &sm[b][0];
        const short* Bb = &sm[b][16384];
        const int tn  = (t + 1 < nkt) ? t + 1 : nkt - 1;   // clamped: keep issue counts exact
        const int tnn = (t + 2 < nkt) ? t + 2 : nkt - 1;

        short8 a0[4], a1[4], bf0[4], bf1[4];

        // ---- P0: kk0, m0-3 ---- stage B-U0..3(t+1) -> buf b^1
        LD_A(Ab, 0, 0, a0);
        LD_B(Bb, 0, bf0);
        STAGE_B(0, tn, b ^ 1); STAGE_B(1, tn, b ^ 1); STAGE_B(2, tn, b ^ 1); STAGE_B(3, tn, b ^ 1);
        BARRIER();
        __builtin_amdgcn_s_setprio(1);
#pragma unroll
        for (int m = 0; m < 4; ++m)
#pragma unroll
            for (int n = 0; n < 4; ++n)
                acc[m][n] = __builtin_amdgcn_mfma_f32_16x16x32_bf16(a0[m], bf0[n], acc[m][n], 0, 0, 0);
        __builtin_amdgcn_s_setprio(0);
        LGKM0();
        BARRIER();

        // ---- P1: kk0, m4-7 ---- stage A-U1,U3(t+1) -> buf b^1
        LD_A(Ab, 1, 0, a1);
        STAGE_A(1, tn, b ^ 1); STAGE_A(3, tn, b ^ 1);
        BARRIER();
        __builtin_amdgcn_s_setprio(1);
#pragma unroll
        for (int m = 0; m < 4; ++m)
#pragma unroll
            for (int n = 0; n < 4; ++n)
                acc[4 + m][n] = __builtin_amdgcn_mfma_f32_16x16x32_bf16(a1[m], bf0[n], acc[4 + m][n], 0, 0, 0);
        __builtin_amdgcn_s_setprio(0);
        LGKM0();
        BARRIER();

        // ---- P2: kk1, m0-3 ---- (no stage)
        LD_A(Ab, 0, 1, a0);
        LD_B(Bb, 1, bf1);
        BARRIER();
        __builtin_amdgcn_s_setprio(1);
#pragma unroll
        for (int m = 0; m < 4; ++m)
#pragma unroll
            for (int n = 0; n < 4; ++n)
                acc[m][n] = __builtin_amdgcn_mfma_f32_16x16x32_bf16(a0[m], bf1[n], acc[m][n], 0, 0, 0);
        __builtin_amdgcn_s_setprio(0);
        LGKM0();
        BARRIER();

        // ---- P3: kk1, m4-7 ---- stage A-U0,U2(t+2) -> buf b (just freed at P2)
        LD_A(Ab, 1, 1, a1);
        STAGE_A(0, tnn, b); STAGE_A(2, tnn, b);
        BARRIER();
        __builtin_amdgcn_s_setprio(1);
#pragma unroll
        for (int m = 0; m < 4; ++m)
#pragma unroll
            for (int n = 0; n < 4; ++n)
                acc[4 + m][n] = __builtin_amdgcn_mfma_f32_16x16x32_bf16(a1[m], bf1[n], acc[4 + m][n], 0, 0, 0);
        __builtin_amdgcn_s_setprio(0);
        LGKM0();
        VMCNT2();          // retire all of tile t+1 (8 units); leave A-U0,U2(t+2) in flight
        BARRIER();
    }

    // ---- epilogue: C = acc + bias (fp32) ----
    const int r0 = bm * 256 + wr * 128 + (lane >> 4) * 4;
    const int c0 = bn * 256 + wc * 64 + (lane & 15);
#pragma unroll
    for (int n = 0; n < 4; ++n) {
        float bv = bias[c0 + n * 16];
#pragma unroll
        for (int m = 0; m < 8; ++m) {
#pragma unroll
            for (int r = 0; r < 4; ++r) {
                C[(size_t)(r0 + m * 16 + r) * N + (c0 + n * 16)] = acc[m][n][r] + bv;
            }
        }
    }
}

// ---- fallback (shape-generic, slow but correct) -----------------------------
__global__ void fallback_gemm(const float* __restrict__ x, const float* __restrict__ w,
                              const float* __restrict__ sinv, const float* __restrict__ bias,
                              float* __restrict__ out, int M, int N, int K) {
    int n = blockIdx.x * 64 + (threadIdx.x & 63);
    int m = blockIdx.y * 4 + (threadIdx.x >> 6);
    if (m >= M || n >= N) return;
    const int nbk = K >> 7;
    float acc = 0.f;
    for (int k = 0; k < K; ++k)
        acc += x[(size_t)m * K + k] * w[(size_t)n * K + k] * sinv[(n >> 7) * nbk + (k >> 7)];
    out[(size_t)m * N + n] = acc + bias[n];
}

extern "C" void kernel_launch(void* const* d_in, const int* in_sizes, int n_in,
                              void* d_out, int out_size, void* d_ws, size_t ws_size,
                              hipStream_t stream) {
    const float* x    = (const float*)d_in[0];
    const float* w    = (const float*)d_in[1];
    const float* sinv = (const float*)d_in[2];
    const float* bias = (const float*)d_in[3];
    float* out        = (float*)d_out;

    const int O = in_sizes[3];                  // 4096
    const int K = in_sizes[1] / O;              // 4096
    const int M = (int)((long)in_sizes[0] / K); // B*S = 4096
    const int N = O;

    const size_t need = ((size_t)M * K + (size_t)N * K) * sizeof(ushort);
    const int nwg = (M / 256) * (N / 256);
    const bool ok = ws_size >= need && (M % 256 == 0) && (N % 256 == 0) &&
                    (K % 128 == 0) && (nwg % 8 == 0) && ((long)M * K % 2048 == 0) &&
                    (K % 2048 == 0);
    if (ok) {
        ushort* xb = (ushort*)d_ws;
        ushort* wb = xb + (size_t)M * K;
        long n8 = (long)M * K / 8;
        conv_x_kernel<<<dim3((unsigned)(n8 / 256)), 256, 0, stream>>>(x, xb, n8);
        conv_w_kernel<<<dim3(K / 2048, N), 256, 0, stream>>>(w, sinv, wb, K, K >> 7);
        gemm256_kernel<<<dim3(nwg), 512, 0, stream>>>(xb, wb, bias, out, M, N, K);
    } else {
        dim3 g(N / 64, (M + 3) / 4);
        fallback_gemm<<<g, 256, 0, stream>>>(x, w, sinv, bias, out, M, N, K);
    }
}